// Round 4
// baseline (230.716 us; speedup 1.0000x reference)
//
#include <hip/hip_runtime.h>

#define KI 50

// LDS float layout (stride-68 rows; 68*4=272 B rows, 16B-aligned row starts):
//  X0 [0,4624)      68x68: x ch0 at (g+2,c+2)   -- reused as vA: v(g,c) at (g+1,c+2)
//  X1 [4624,9248)   68x68: x ch1                -- reused as vB
//  R  [9248,13736)  66x68: r(g,c) at (g+1,c+2); first used to stage r_w/h_w/h_b (4200)
//  W  [13736,14208) w2[0,162) rhb[162,171) qb[171,181) rb[181] fcw[182,262)
//                   qw0[262,352) (c*9+j)  qwl[352,472) (c*12+j, 16B-aligned, pads=0)
#define X1_OFF 4624
#define R_OFF 9248
#define W_OFF 13736
#define LDS_TOT 14208

__device__ __forceinline__ void vi_step(const float* __restrict__ cur, float* __restrict__ nxt,
                                        const float* __restrict__ SW,
                                        int row, int c0, const float (&qr)[10][8]) {
    float nb[3][12];
#pragma unroll
    for (int dy = 0; dy < 3; ++dy) {
        const float* lp = cur + (row + dy) * 68 + c0;
        float4 a0 = *(const float4*)lp;
        float4 a1 = *(const float4*)(lp + 4);
        float4 a2 = *(const float4*)(lp + 8);
        nb[dy][0] = a0.x; nb[dy][1] = a0.y; nb[dy][2]  = a0.z; nb[dy][3]  = a0.w;
        nb[dy][4] = a1.x; nb[dy][5] = a1.y; nb[dy][6]  = a1.z; nb[dy][7]  = a1.w;
        nb[dy][8] = a2.x; nb[dy][9] = a2.y; nb[dy][10] = a2.z; nb[dy][11] = a2.w;
    }
    float vmax[8];
#pragma unroll
    for (int c = 0; c < 10; ++c) {
        const float4* wc = (const float4*)(SW + 352 + c * 12);   // wave-uniform broadcast
        float4 w0 = wc[0], w1 = wc[1], w2v = wc[2];
        float w[9] = {w0.x, w0.y, w0.z, w0.w, w1.x, w1.y, w1.z, w1.w, w2v.x};
#pragma unroll
        for (int p = 0; p < 8; ++p) {
            float acc = qr[c][p];
#pragma unroll
            for (int ky = 0; ky < 3; ++ky)
#pragma unroll
                for (int kx = 0; kx < 3; ++kx)
                    acc = fmaf(w[ky * 3 + kx], nb[ky][p + kx + 1], acc);
            vmax[p] = c ? fmaxf(vmax[p], acc) : acc;
        }
    }
    float* wp = nxt + (row + 1) * 68 + 2 + c0;   // 8B-aligned
#pragma unroll
    for (int j = 0; j < 4; ++j)
        *(float2*)(wp + 2 * j) = make_float2(vmax[2 * j], vmax[2 * j + 1]);
}

__launch_bounds__(512, 1)
__global__ void vin_main(const float* __restrict__ x,
                         const int* __restrict__ pos_x, const int* __restrict__ pos_y,
                         const float* __restrict__ h_w, const float* __restrict__ h_b,
                         const float* __restrict__ r_w, const float* __restrict__ r_b,
                         const float* __restrict__ q_w, const float* __restrict__ q_b,
                         const float* __restrict__ fc_w, float* __restrict__ out) {
    __shared__ __align__(16) float S[LDS_TOT];
    const int tid = threadIdx.x;
    const int b = blockIdx.x;
    const int row = tid >> 3;          // 0..63
    const int c0 = (tid & 7) << 3;     // 0,8,..,56
    float* SW = S + W_OFF;
    float* RL = S + R_OFF;             // weight staging area (phase 1 only)

    // ---- phase 0: zero X0/X1 (rings + interiors): 9248 floats = 2312 quads
    float4 z4 = make_float4(0.f, 0.f, 0.f, 0.f);
    for (int i = tid; i < 2312; i += 512) ((float4*)S)[i] = z4;

    // ---- phase 1a: stage x interior + raw weights (coalesced) into LDS
    {
        const float4* xg = (const float4*)(x + (size_t)b * 8192);
        for (int i = tid; i < 2048; i += 512) {
            float4 v = xg[i];
            int ch = i >> 10, rem = i & 1023;
            int y = rem >> 4, xc = (rem & 15) << 2;
            float* dst = S + ch * 4624 + (y + 2) * 68 + xc + 2;   // 8B-aligned
            *(float2*)dst       = make_float2(v.x, v.y);
            *(float2*)(dst + 2) = make_float2(v.z, v.w);
        }
        for (int i = tid; i < 1350; i += 512) RL[i] = r_w[i];
        for (int i = tid; i < 2700; i += 512) RL[1350 + i] = h_w[i];
        if (tid < 150) RL[4050 + tid] = h_b[tid];
    }
    __syncthreads();

    // ---- phase 1b: composite weights from LDS + fill W region (disjoint tid ranges)
    if (tid < 162) {
        int i = tid / 81, rem = tid % 81, dq = rem / 9, ds = rem % 9;
        float s = 0.f;
#pragma unroll 5
        for (int m = 0; m < 150; ++m)
            s = fmaf(RL[m * 9 + dq], RL[1350 + (m * 2 + i) * 9 + ds], s);
        SW[tid] = s;
    } else if (tid < 171) {
        int dq = tid - 162;
        float s = 0.f;
#pragma unroll 5
        for (int m = 0; m < 150; ++m)
            s = fmaf(RL[m * 9 + dq], RL[4050 + m], s);
        SW[tid] = s;
    } else if (tid < 181) {
        SW[tid] = q_b[tid - 171];
    } else if (tid == 181) {
        SW[181] = r_b[0];
    } else if (tid < 262) {
        SW[tid] = fc_w[tid - 182];
    } else if (tid < 352) {
        int t = tid - 262;
        SW[tid] = q_w[(t / 9) * 18 + (t % 9)];          // qw0: r-part
    } else if (tid < 472) {
        int t = tid - 352, c = t / 12, j = t % 12;
        SW[tid] = (j < 9) ? q_w[c * 18 + 9 + j] : 0.f;  // qwl: v-part, padded
    }
    __syncthreads();

    // ---- phase 2: zero R ring; r = composite 2-stage conv (exact SAME-border clip)
    if (tid < 34) {                                     // rows 0 and 65 (17 quads each)
        int rrow = (tid < 17) ? 0 : 65;
        *(float4*)&S[R_OFF + rrow * 68 + (tid % 17) * 4] = z4;
    } else if (tid >= 64 && tid < 192) {                // side cols rows 1..64
        int t = tid - 64, r = 1 + (t & 63), side = t >> 6;
        *(float2*)&S[R_OFF + r * 68 + (side ? 66 : 0)] = make_float2(0.f, 0.f);
    }
    {
        float xb0[5][12], xb1[5][12];
        const float* X0 = S;
        const float* X1 = S + X1_OFF;
#pragma unroll
        for (int dy = 0; dy < 5; ++dy) {
#pragma unroll
            for (int j = 0; j < 3; ++j) {
                float4 a = *(const float4*)&X0[(row + dy) * 68 + c0 + 4 * j];
                xb0[dy][4 * j + 0] = a.x; xb0[dy][4 * j + 1] = a.y;
                xb0[dy][4 * j + 2] = a.z; xb0[dy][4 * j + 3] = a.w;
                float4 c = *(const float4*)&X1[(row + dy) * 68 + c0 + 4 * j];
                xb1[dy][4 * j + 0] = c.x; xb1[dy][4 * j + 1] = c.y;
                xb1[dy][4 * j + 2] = c.z; xb1[dy][4 * j + 3] = c.w;
            }
        }
        float racc[8];
        float rbv = SW[181];
#pragma unroll
        for (int p = 0; p < 8; ++p) racc[p] = rbv;
#pragma unroll
        for (int dqy = 0; dqy < 3; ++dqy) {
            bool rowok = (row + dqy >= 1) && (row + dqy <= 64);
#pragma unroll
            for (int dqx = 0; dqx < 3; ++dqx) {
                int dq = dqy * 3 + dqx;
                float rh = SW[162 + dq];
                float w20[9], w21[9];
#pragma unroll
                for (int ds = 0; ds < 9; ++ds) {
                    w20[ds] = SW[dq * 9 + ds];
                    w21[ds] = SW[81 + dq * 9 + ds];
                }
#pragma unroll
                for (int p = 0; p < 8; ++p) {
                    float t = rh;
#pragma unroll
                    for (int dsy = 0; dsy < 3; ++dsy)
#pragma unroll
                        for (int dsx = 0; dsx < 3; ++dsx) {
                            int ds = dsy * 3 + dsx;
                            t = fmaf(w20[ds], xb0[dqy + dsy][p + dqx + dsx], t);
                            t = fmaf(w21[ds], xb1[dqy + dsy][p + dqx + dsx], t);
                        }
                    int qx = c0 + p + dqx - 1;
                    bool ok = rowok && (qx >= 0) && (qx < 64);
                    racc[p] += ok ? t : 0.f;
                }
            }
        }
        float* wp = S + R_OFF + (row + 1) * 68 + 2 + c0;
#pragma unroll
        for (int j = 0; j < 4; ++j)
            *(float2*)(wp + 2 * j) = make_float2(racc[2 * j], racc[2 * j + 1]);
    }
    __syncthreads();

    // ---- phase 3: qr (loop-invariant q half) into regs; re-zero vA/vB
    float qr[10][8];
    {
        float rnb[3][12];
        const float* SR = S + R_OFF;
#pragma unroll
        for (int ky = 0; ky < 3; ++ky) {
            const float* lp = SR + (row + ky) * 68 + c0;
            float4 a0 = *(const float4*)lp;
            float4 a1 = *(const float4*)(lp + 4);
            float4 a2 = *(const float4*)(lp + 8);
            rnb[ky][0] = a0.x; rnb[ky][1] = a0.y; rnb[ky][2]  = a0.z; rnb[ky][3]  = a0.w;
            rnb[ky][4] = a1.x; rnb[ky][5] = a1.y; rnb[ky][6]  = a1.z; rnb[ky][7]  = a1.w;
            rnb[ky][8] = a2.x; rnb[ky][9] = a2.y; rnb[ky][10] = a2.z; rnb[ky][11] = a2.w;
        }
#pragma unroll
        for (int c = 0; c < 10; ++c) {
            float qbc = SW[171 + c];
            float w[9];
#pragma unroll
            for (int j = 0; j < 9; ++j) w[j] = SW[262 + c * 9 + j];
#pragma unroll
            for (int p = 0; p < 8; ++p) {
                float acc = qbc;
#pragma unroll
                for (int ky = 0; ky < 3; ++ky)
#pragma unroll
                    for (int kx = 0; kx < 3; ++kx)
                        acc = fmaf(w[ky * 3 + kx], rnb[ky][p + kx + 1], acc);
                qr[c][p] = acc;
            }
        }
        // re-zero vA/vB region (held x data); v0 = 0, rings stay 0 forever
        for (int i = tid; i < 2312; i += 512) ((float4*)S)[i] = z4;
    }
    __syncthreads();

    // ---- phase 4: 50 VI steps, double-buffered v in LDS (ends in vA)
    float* vA = S;
    float* vB = S + X1_OFF;
#pragma unroll 1
    for (int k = 0; k < KI / 2; ++k) {
        vi_step(vA, vB, SW, row, c0, qr);
        __syncthreads();
        vi_step(vB, vA, SW, row, c0, qr);
        __syncthreads();
    }

    // ---- phase 5: readout at (pos_x, pos_y) + FC by the owning thread
    int pr = pos_x[b], pc = pos_y[b];
    if (row == pr && (pc >> 3) == (tid & 7)) {
        int p = pc & 7;
        float qf[10];
#pragma unroll
        for (int c = 0; c < 10; ++c) {
            float acc = qr[c][p];
#pragma unroll
            for (int ky = 0; ky < 3; ++ky)
#pragma unroll
                for (int kx = 0; kx < 3; ++kx)
                    acc = fmaf(SW[352 + c * 12 + 3 * ky + kx],
                               vA[(pr + ky) * 68 + pc + 1 + kx], acc);
            qf[c] = acc;
        }
#pragma unroll
        for (int o = 0; o < 8; ++o) {
            float s = 0.f;
#pragma unroll
            for (int c = 0; c < 10; ++c) s = fmaf(SW[182 + o * 10 + c], qf[c], s);
            out[b * 8 + o] = s;
        }
    }
}

extern "C" void kernel_launch(void* const* d_in, const int* in_sizes, int n_in,
                              void* d_out, int out_size, void* d_ws, size_t ws_size,
                              hipStream_t stream) {
    const float* x     = (const float*)d_in[0];
    const int*   pos_x = (const int*)d_in[1];
    const int*   pos_y = (const int*)d_in[2];
    const float* h_w   = (const float*)d_in[3];
    const float* h_b   = (const float*)d_in[4];
    const float* r_w   = (const float*)d_in[5];
    const float* r_b   = (const float*)d_in[6];
    const float* q_w   = (const float*)d_in[7];
    const float* q_b   = (const float*)d_in[8];
    const float* fc_w  = (const float*)d_in[9];
    float* out = (float*)d_out;

    vin_main<<<128, 512, 0, stream>>>(x, pos_x, pos_y, h_w, h_b, r_w, r_b,
                                      q_w, q_b, fc_w, out);
}

// Round 5
// 208.939 us; speedup vs baseline: 1.1042x; 1.1042x over previous
//
#include <hip/hip_runtime.h>

#define KI 50

// LDS float layout (stride-68 rows; 68*4=272 B rows, 16B-aligned row starts):
//  X0 [0,4624)      68x68: x ch0 at (g+2,c+2)   -- reused as vA: v(g,c) at (g+1,c+2)
//  X1 [4624,9248)   68x68: x ch1                -- reused as vB
//  R  [9248,13736)  66x68: r(g,c) at (g+1,c+2); first stages r_w/h_w/h_b (4200 floats)
//  W  [13736,14178) w2[0,162) rhb[162,171) qb[171,181) rb[181] fcw[182,262) qw[262,442)
#define X1_OFF 4624
#define R_OFF 9248
#define W_OFF 13736
#define LDS_TOT 14178

// NOTE: qr/qwv are only ever indexed by compile-time constants (fully unrolled
// loops). Any runtime index into these arrays demotes them to scratch -> 20 MB
// of per-iteration L2 traffic (measured R1/R3/R4). Phase 5 therefore recomputes
// from LDS instead of touching these arrays.
__device__ __forceinline__ void vi_step(const float* __restrict__ cur, float* __restrict__ nxt,
                                        int row, int c0,
                                        const float (&qr)[10][8], const float (&qwv)[10][9]) {
    float nb[3][12];
#pragma unroll
    for (int dy = 0; dy < 3; ++dy) {
        const float* lp = cur + (row + dy) * 68 + c0;
        float4 a0 = *(const float4*)lp;
        float4 a1 = *(const float4*)(lp + 4);
        float4 a2 = *(const float4*)(lp + 8);
        nb[dy][0] = a0.x; nb[dy][1] = a0.y; nb[dy][2]  = a0.z; nb[dy][3]  = a0.w;
        nb[dy][4] = a1.x; nb[dy][5] = a1.y; nb[dy][6]  = a1.z; nb[dy][7]  = a1.w;
        nb[dy][8] = a2.x; nb[dy][9] = a2.y; nb[dy][10] = a2.z; nb[dy][11] = a2.w;
    }
    float vmax[8];
#pragma unroll
    for (int c = 0; c < 10; ++c) {
#pragma unroll
        for (int p = 0; p < 8; ++p) {
            float acc = qr[c][p];
#pragma unroll
            for (int ky = 0; ky < 3; ++ky)
#pragma unroll
                for (int kx = 0; kx < 3; ++kx)
                    acc = fmaf(qwv[c][ky * 3 + kx], nb[ky][p + kx + 1], acc);
            vmax[p] = c ? fmaxf(vmax[p], acc) : acc;
        }
    }
    float* wp = nxt + (row + 1) * 68 + 2 + c0;   // 8B-aligned
#pragma unroll
    for (int j = 0; j < 4; ++j)
        *(float2*)(wp + 2 * j) = make_float2(vmax[2 * j], vmax[2 * j + 1]);
}

__launch_bounds__(512, 2)
__global__ void vin_main(const float* __restrict__ x,
                         const int* __restrict__ pos_x, const int* __restrict__ pos_y,
                         const float* __restrict__ h_w, const float* __restrict__ h_b,
                         const float* __restrict__ r_w, const float* __restrict__ r_b,
                         const float* __restrict__ q_w, const float* __restrict__ q_b,
                         const float* __restrict__ fc_w, float* __restrict__ out) {
    __shared__ __align__(16) float S[LDS_TOT];
    const int tid = threadIdx.x;
    const int b = blockIdx.x;
    const int row = tid >> 3;          // 0..63
    const int c0 = (tid & 7) << 3;     // 0,8,..,56
    float* SW = S + W_OFF;
    float* RL = S + R_OFF;             // weight staging area (phase 1 only)

    // ---- phase 0: zero X0/X1 (rings + interiors): 9248 floats = 2312 quads
    float4 z4 = make_float4(0.f, 0.f, 0.f, 0.f);
    for (int i = tid; i < 2312; i += 512) ((float4*)S)[i] = z4;

    // ---- phase 1a: stage x interior + raw weights (coalesced) into LDS
    {
        const float4* xg = (const float4*)(x + (size_t)b * 8192);
        for (int i = tid; i < 2048; i += 512) {
            float4 v = xg[i];
            int ch = i >> 10, rem = i & 1023;
            int y = rem >> 4, xc = (rem & 15) << 2;
            float* dst = S + ch * 4624 + (y + 2) * 68 + xc + 2;   // 8B-aligned
            *(float2*)dst       = make_float2(v.x, v.y);
            *(float2*)(dst + 2) = make_float2(v.z, v.w);
        }
        for (int i = tid; i < 1350; i += 512) RL[i] = r_w[i];
        for (int i = tid; i < 2700; i += 512) RL[1350 + i] = h_w[i];
        if (tid < 150) RL[4050 + tid] = h_b[tid];
    }
    __syncthreads();

    // ---- phase 1b: composite weights from LDS + fill W region (disjoint tid ranges)
    if (tid < 162) {
        int i = tid / 81, rem = tid % 81, dq = rem / 9, ds = rem % 9;
        float s = 0.f;
#pragma unroll 5
        for (int m = 0; m < 150; ++m)
            s = fmaf(RL[m * 9 + dq], RL[1350 + (m * 2 + i) * 9 + ds], s);
        SW[tid] = s;
    } else if (tid < 171) {
        int dq = tid - 162;
        float s = 0.f;
#pragma unroll 5
        for (int m = 0; m < 150; ++m)
            s = fmaf(RL[m * 9 + dq], RL[4050 + m], s);
        SW[tid] = s;
    } else if (tid < 181) {
        SW[tid] = q_b[tid - 171];
    } else if (tid == 181) {
        SW[181] = r_b[0];
    } else if (tid < 262) {
        SW[tid] = fc_w[tid - 182];
    } else if (tid < 442) {
        SW[tid] = q_w[tid - 262];     // raw q_w, both halves, layout c*18+j
    }
    __syncthreads();

    // ---- phase 2: zero R ring; r = composite 2-stage conv (exact SAME-border clip)
    if (tid < 34) {                                     // rows 0 and 65 (17 quads each)
        int rrow = (tid < 17) ? 0 : 65;
        *(float4*)&S[R_OFF + rrow * 68 + (tid % 17) * 4] = z4;
    } else if (tid >= 64 && tid < 192) {                // side words 0,1 / 66,67, rows 1..64
        int t = tid - 64, r = 1 + (t & 63), side = t >> 6;
        *(float2*)&S[R_OFF + r * 68 + (side ? 66 : 0)] = make_float2(0.f, 0.f);
    }
    {
        float xb0[5][12], xb1[5][12];
        const float* X0 = S;
        const float* X1 = S + X1_OFF;
#pragma unroll
        for (int dy = 0; dy < 5; ++dy) {
#pragma unroll
            for (int j = 0; j < 3; ++j) {
                float4 a = *(const float4*)&X0[(row + dy) * 68 + c0 + 4 * j];
                xb0[dy][4 * j + 0] = a.x; xb0[dy][4 * j + 1] = a.y;
                xb0[dy][4 * j + 2] = a.z; xb0[dy][4 * j + 3] = a.w;
                float4 c = *(const float4*)&X1[(row + dy) * 68 + c0 + 4 * j];
                xb1[dy][4 * j + 0] = c.x; xb1[dy][4 * j + 1] = c.y;
                xb1[dy][4 * j + 2] = c.z; xb1[dy][4 * j + 3] = c.w;
            }
        }
        float racc[8];
        float rbv = SW[181];
#pragma unroll
        for (int p = 0; p < 8; ++p) racc[p] = rbv;
#pragma unroll
        for (int dqy = 0; dqy < 3; ++dqy) {
            bool rowok = (row + dqy >= 1) && (row + dqy <= 64);
#pragma unroll
            for (int dqx = 0; dqx < 3; ++dqx) {
                int dq = dqy * 3 + dqx;
                float rh = SW[162 + dq];
                float w20[9], w21[9];
#pragma unroll
                for (int ds = 0; ds < 9; ++ds) {
                    w20[ds] = SW[dq * 9 + ds];
                    w21[ds] = SW[81 + dq * 9 + ds];
                }
#pragma unroll
                for (int p = 0; p < 8; ++p) {
                    float t = rh;
#pragma unroll
                    for (int dsy = 0; dsy < 3; ++dsy)
#pragma unroll
                        for (int dsx = 0; dsx < 3; ++dsx) {
                            int ds = dsy * 3 + dsx;
                            t = fmaf(w20[ds], xb0[dqy + dsy][p + dqx + dsx], t);
                            t = fmaf(w21[ds], xb1[dqy + dsy][p + dqx + dsx], t);
                        }
                    int qx = c0 + p + dqx - 1;
                    bool ok = rowok && (qx >= 0) && (qx < 64);
                    racc[p] += ok ? t : 0.f;
                }
            }
        }
        float* wp = S + R_OFF + (row + 1) * 68 + 2 + c0;
#pragma unroll
        for (int j = 0; j < 4; ++j)
            *(float2*)(wp + 2 * j) = make_float2(racc[2 * j], racc[2 * j + 1]);
    }
    __syncthreads();

    // ---- phase 3: qr (loop-invariant q half) + qwv into regs; re-zero vA/vB
    float qr[10][8];
    float qwv[10][9];
    {
        float rnb[3][12];
        const float* SR = S + R_OFF;
#pragma unroll
        for (int ky = 0; ky < 3; ++ky) {
            const float* lp = SR + (row + ky) * 68 + c0;
            float4 a0 = *(const float4*)lp;
            float4 a1 = *(const float4*)(lp + 4);
            float4 a2 = *(const float4*)(lp + 8);
            rnb[ky][0] = a0.x; rnb[ky][1] = a0.y; rnb[ky][2]  = a0.z; rnb[ky][3]  = a0.w;
            rnb[ky][4] = a1.x; rnb[ky][5] = a1.y; rnb[ky][6]  = a1.z; rnb[ky][7]  = a1.w;
            rnb[ky][8] = a2.x; rnb[ky][9] = a2.y; rnb[ky][10] = a2.z; rnb[ky][11] = a2.w;
        }
#pragma unroll
        for (int c = 0; c < 10; ++c) {
            float qbc = SW[171 + c];
            float w[9];
#pragma unroll
            for (int j = 0; j < 9; ++j) w[j] = SW[262 + c * 18 + j];
#pragma unroll
            for (int p = 0; p < 8; ++p) {
                float acc = qbc;
#pragma unroll
                for (int ky = 0; ky < 3; ++ky)
#pragma unroll
                    for (int kx = 0; kx < 3; ++kx)
                        acc = fmaf(w[ky * 3 + kx], rnb[ky][p + kx + 1], acc);
                qr[c][p] = acc;
            }
        }
#pragma unroll
        for (int c = 0; c < 10; ++c)
#pragma unroll
            for (int j = 0; j < 9; ++j) qwv[c][j] = SW[262 + c * 18 + 9 + j];
        // re-zero vA/vB region (held x data); v0 = 0, rings stay 0 forever
        for (int i = tid; i < 2312; i += 512) ((float4*)S)[i] = z4;
    }
    __syncthreads();

    // ---- phase 4: 50 VI steps, double-buffered v in LDS (ends in vA)
    float* vA = S;
    float* vB = S + X1_OFF;
#pragma unroll 1
    for (int k = 0; k < KI / 2; ++k) {
        vi_step(vA, vB, row, c0, qr, qwv);
        __syncthreads();
        vi_step(vB, vA, row, c0, qr, qwv);
        __syncthreads();
    }

    // ---- phase 5: readout at (pos_x, pos_y) + FC, all-LDS (no dynamic reg-array
    // indexing!). R is still intact in LDS; v final is in vA. One thread per block.
    if (tid == 0) {
        int pr = pos_x[b], pc = pos_y[b];
        const float* Rp = S + R_OFF;
        float qf[10];
#pragma unroll
        for (int c = 0; c < 10; ++c) {
            float acc = SW[171 + c];
#pragma unroll
            for (int ky = 0; ky < 3; ++ky)
#pragma unroll
                for (int kx = 0; kx < 3; ++kx) {
                    int off = (pr + ky) * 68 + pc + 1 + kx;   // ring zeros handle borders
                    acc = fmaf(SW[262 + c * 18 + ky * 3 + kx], Rp[off], acc);
                    acc = fmaf(SW[262 + c * 18 + 9 + ky * 3 + kx], vA[off], acc);
                }
            qf[c] = acc;
        }
#pragma unroll
        for (int o = 0; o < 8; ++o) {
            float s = 0.f;
#pragma unroll
            for (int c = 0; c < 10; ++c) s = fmaf(SW[182 + o * 10 + c], qf[c], s);
            out[b * 8 + o] = s;
        }
    }
}

extern "C" void kernel_launch(void* const* d_in, const int* in_sizes, int n_in,
                              void* d_out, int out_size, void* d_ws, size_t ws_size,
                              hipStream_t stream) {
    const float* x     = (const float*)d_in[0];
    const int*   pos_x = (const int*)d_in[1];
    const int*   pos_y = (const int*)d_in[2];
    const float* h_w   = (const float*)d_in[3];
    const float* h_b   = (const float*)d_in[4];
    const float* r_w   = (const float*)d_in[5];
    const float* r_b   = (const float*)d_in[6];
    const float* q_w   = (const float*)d_in[7];
    const float* q_b   = (const float*)d_in[8];
    const float* fc_w  = (const float*)d_in[9];
    float* out = (float*)d_out;

    vin_main<<<128, 512, 0, stream>>>(x, pos_x, pos_y, h_w, h_b, r_w, r_b,
                                      q_w, q_b, fc_w, out);
}